// Round 1
// baseline (143.306 us; speedup 1.0000x reference)
//
#include <hip/hip_runtime.h>

// SoftSymmetricAlignment: B=4, N=M=512, D=128, fp32.
// z[b,n,m] = sum_d |x[b,n,d]-y[b,m,d]|; alpha=softmax_n(-z), beta=softmax_m(-z)
// over valid region only (masked entries underflow to exactly 0 in fp32);
// a = alpha+beta-alpha*beta; out[b] = -sum(a*z)/sum(a).

constexpr int B = 4, N = 512, M = 512, D = 128;
constexpr int TN = 64, TM = 64;
constexpr int LSTR = D + 4;           // +4 floats pad: rows shift 4 banks -> <=2-way conflicts
#define SENT -3.0e38f                  // "minus infinity" that is exp-safe (no inf-inf NaN)

// lengths: jnp.int64 in the reference, but JAX w/o x64 gives int32. Lengths are
// >=64, so odd int32 slots are 0 iff the buffer is int64 little-endian.
__device__ __forceinline__ int load_len(const int* p, int b) {
  bool is64 = (p[1] == 0) && (p[3] == 0);
  return is64 ? p[2 * b] : p[b];
}

__global__ __launch_bounds__(256) void k_zdiff(const float* __restrict__ x,
                                               const float* __restrict__ y,
                                               float* __restrict__ z) {
  __shared__ float xs[TN * LSTR];
  __shared__ float ys[TM * LSTR];
  const int b  = blockIdx.z;
  const int n0 = blockIdx.y * TN;
  const int m0 = blockIdx.x * TM;
  const int tid = threadIdx.x;

  // Tiles are contiguous 32KB chunks in global (full D range, consecutive rows).
  const float4* xg = (const float4*)(x + (size_t)(b * N + n0) * D);
  const float4* yg = (const float4*)(y + (size_t)(b * M + m0) * D);
#pragma unroll
  for (int k = 0; k < 8; ++k) {
    int idx = tid + k * 256;     // float4 index within tile (2048 total)
    int r = idx >> 5;            // 32 float4 per row
    int c = (idx & 31) << 2;     // float offset within row
    *(float4*)&xs[r * LSTR + c] = xg[idx];
    *(float4*)&ys[r * LSTR + c] = yg[idx];
  }
  __syncthreads();

  const int tx = tid & 15;       // m group
  const int ty = tid >> 4;       // n group
  float acc[4][4];
#pragma unroll
  for (int i = 0; i < 4; ++i)
#pragma unroll
    for (int j = 0; j < 4; ++j) acc[i][j] = 0.f;

  // Micro-tile is STRIDED (n = n0+ty+16i, m = m0+tx+16j): within a wave the 16
  // tx lanes hit rows tx+16j -> banks 4*tx%32 = 2-way (free); x reads broadcast.
#pragma unroll 4
  for (int dd = 0; dd < D; dd += 4) {
    float4 xa[4], yb[4];
#pragma unroll
    for (int i = 0; i < 4; ++i) xa[i] = *(const float4*)&xs[(ty + 16 * i) * LSTR + dd];
#pragma unroll
    for (int j = 0; j < 4; ++j) yb[j] = *(const float4*)&ys[(tx + 16 * j) * LSTR + dd];
#pragma unroll
    for (int i = 0; i < 4; ++i)
#pragma unroll
      for (int j = 0; j < 4; ++j) {
        acc[i][j] += fabsf(xa[i].x - yb[j].x);
        acc[i][j] += fabsf(xa[i].y - yb[j].y);
        acc[i][j] += fabsf(xa[i].z - yb[j].z);
        acc[i][j] += fabsf(xa[i].w - yb[j].w);
      }
  }

  float* zb = z + (size_t)b * N * M;
#pragma unroll
  for (int i = 0; i < 4; ++i) {
    int n = n0 + ty + 16 * i;
#pragma unroll
    for (int j = 0; j < 4; ++j) {
      int m = m0 + tx + 16 * j;
      zb[n * M + m] = acc[i][j];
    }
  }
}

// blockIdx.z==0: column stats (softmax over n, per m). blockIdx.z==1: row stats.
// Stores max(w) and RECIPROCAL of sum(exp(w-max)), w=-z, over valid region only.
__global__ __launch_bounds__(256) void k_stats(const float* __restrict__ z,
                                               const int* __restrict__ xlen,
                                               const int* __restrict__ ylen,
                                               float* __restrict__ cmax, float* __restrict__ csuminv,
                                               float* __restrict__ rmax, float* __restrict__ rsuminv) {
  const int b = blockIdx.y;
  const int xl = load_len(xlen, b);
  const int yl = load_len(ylen, b);
  const float* zb = z + (size_t)b * N * M;
  const int tid  = threadIdx.x;
  const int lane = tid & 63;
  const int wave = tid >> 6;

  if (blockIdx.z == 0) {
    // columns m0..m0+63; 4 waves stripe the n range
    const int m = blockIdx.x * 64 + lane;
    __shared__ float smx[4][64];
    __shared__ float ssm[4][64];
    float mx = SENT;
    for (int n = wave; n < xl; n += 4) mx = fmaxf(mx, -zb[n * M + m]);
    smx[wave][lane] = mx;
    __syncthreads();
    float gmx = fmaxf(fmaxf(smx[0][lane], smx[1][lane]), fmaxf(smx[2][lane], smx[3][lane]));
    float s = 0.f;
    for (int n = wave; n < xl; n += 4) s += __expf(-zb[n * M + m] - gmx);
    ssm[wave][lane] = s;
    __syncthreads();
    if (wave == 0) {
      float gs = ssm[0][lane] + ssm[1][lane] + ssm[2][lane] + ssm[3][lane];
      cmax[b * M + m]    = gmx;
      csuminv[b * M + m] = 1.0f / gs;
    }
  } else {
    // rows n0..n0+63; one wave per row, 16 rows per wave
    const int n0 = blockIdx.x * 64;
    for (int k = 0; k < 16; ++k) {
      int n = n0 + wave * 16 + k;
      if (n >= xl) continue;               // uniform across the wave
      const float* zr = zb + (size_t)n * M;
      float mx = SENT;
      for (int m = lane; m < yl; m += 64) mx = fmaxf(mx, -zr[m]);
#pragma unroll
      for (int off = 32; off > 0; off >>= 1) mx = fmaxf(mx, __shfl_xor(mx, off, 64));
      float s = 0.f;
      for (int m = lane; m < yl; m += 64) s += __expf(-zr[m] - mx);
#pragma unroll
      for (int off = 32; off > 0; off >>= 1) s += __shfl_xor(s, off, 64);
      if (lane == 0) { rmax[b * N + n] = mx; rsuminv[b * N + n] = 1.0f / s; }
    }
  }
}

__global__ __launch_bounds__(256) void k_final(const float* __restrict__ z,
                                               const int* __restrict__ xlen,
                                               const int* __restrict__ ylen,
                                               const float* __restrict__ cmax,
                                               const float* __restrict__ csuminv,
                                               const float* __restrict__ rmax,
                                               const float* __restrict__ rsuminv,
                                               float* __restrict__ acc) {
  const int b = blockIdx.y;
  const int xl = load_len(xlen, b);
  const int yl = load_len(ylen, b);
  const int n0 = blockIdx.x * 8;
  const float* zb = z + (size_t)b * N * M;
  const int tid = threadIdx.x;
  float num = 0.f, den = 0.f;
  for (int k = 0; k < 8; ++k) {
    int n = n0 + k;
    if (n >= xl) break;                    // xl uniform across block
    float rm = rmax[b * N + n];
    float ri = rsuminv[b * N + n];
    const float* zr = zb + (size_t)n * M;
    for (int m = tid; m < yl; m += 256) {
      float zv = zr[m];
      float w = -zv;
      float alpha = __expf(w - cmax[b * M + m]) * csuminv[b * M + m];
      float beta  = __expf(w - rm) * ri;
      float a = alpha + beta - alpha * beta;
      num += a * zv;
      den += a;
    }
  }
#pragma unroll
  for (int off = 32; off > 0; off >>= 1) {
    num += __shfl_xor(num, off, 64);
    den += __shfl_xor(den, off, 64);
  }
  if ((tid & 63) == 0) {
    atomicAdd(&acc[b], num);
    atomicAdd(&acc[B + b], den);
  }
}

__global__ void k_out(const float* __restrict__ acc, float* __restrict__ out) {
  int b = threadIdx.x;
  if (b < B) out[b] = -acc[b] / acc[B + b];
}

extern "C" void kernel_launch(void* const* d_in, const int* in_sizes, int n_in,
                              void* d_out, int out_size, void* d_ws, size_t ws_size,
                              hipStream_t stream) {
  const float* x    = (const float*)d_in[0];
  const float* y    = (const float*)d_in[1];
  const int*   xlen = (const int*)d_in[2];
  const int*   ylen = (const int*)d_in[3];
  float* out = (float*)d_out;

  float* ws = (float*)d_ws;
  float* z       = ws;              size_t off = (size_t)B * N * M;   // 4 MB
  float* cmax    = ws + off;        off += B * M;
  float* csuminv = ws + off;        off += B * M;
  float* rmax    = ws + off;        off += B * N;
  float* rsuminv = ws + off;        off += B * N;
  float* acc     = ws + off;        off += 2 * B;

  hipMemsetAsync(acc, 0, 2 * B * sizeof(float), stream);
  k_zdiff<<<dim3(M / TM, N / TN, B), 256, 0, stream>>>(x, y, z);
  k_stats<<<dim3(8, B, 2), 256, 0, stream>>>(z, xlen, ylen, cmax, csuminv, rmax, rsuminv);
  k_final<<<dim3(N / 8, B), 256, 0, stream>>>(z, xlen, ylen, cmax, csuminv, rmax, rsuminv, acc);
  k_out<<<1, 64, 0, stream>>>(acc, out);
}

// Round 2
// 108.499 us; speedup vs baseline: 1.3208x; 1.3208x over previous
//
#include <hip/hip_runtime.h>

// SoftSymmetricAlignment: B=4, N=M=512, D=128, fp32.
// z[b,n,m] = sum_d |x[b,n,d]-y[b,m,d]|; alpha=softmax_n(-z), beta=softmax_m(-z)
// over the valid region only (masked -1e9 entries underflow to exactly 0);
// a = alpha+beta-alpha*beta; out[b] = -sum(a*z)/sum(a).
//
// R2: softmax stats fused into k_zdiff (per-tile partials via shfl/LDS
// reductions, online-softmax merge in tiny k_merge) — removes the 42 us
// latency-bound k_stats pass entirely.

constexpr int B = 4, N = 512, M = 512, D = 128;
constexpr int TN = 64, TM = 64;
constexpr int LSTR = D + 4;           // +4 floats pad: rows shift 4 banks -> <=2-way conflicts
#define SENT -3.0e38f                  // "minus infinity" that is exp-safe (no inf-inf NaN)

// lengths: jnp.int64 in the reference, but JAX w/o x64 gives int32. Lengths are
// >=64, so odd int32 slots are 0 iff the buffer is int64 little-endian.
__device__ __forceinline__ int load_len(const int* p, int b) {
  bool is64 = (p[1] == 0) && (p[3] == 0);
  return is64 ? p[2 * b] : p[b];
}

// Fused: z tile + per-tile softmax partials.
//   rp[b][mt][n] = (max, sumexp) of w=-z over this m-tile's valid m, for row n
//   cp[b][nt][m] = (max, sumexp) of w=-z over this n-tile's valid n, for col m
__global__ __launch_bounds__(256) void k_zdiff(const float* __restrict__ x,
                                               const float* __restrict__ y,
                                               const int* __restrict__ xlen,
                                               const int* __restrict__ ylen,
                                               float* __restrict__ z,
                                               float2* __restrict__ rp,
                                               float2* __restrict__ cp) {
  __shared__ float xs[TN * LSTR];
  __shared__ float ys[TM * LSTR];
  __shared__ float2 colp[4][TM];
  const int b  = blockIdx.z;
  const int n0 = blockIdx.y * TN;
  const int m0 = blockIdx.x * TM;
  const int tid = threadIdx.x;
  const int xl = load_len(xlen, b);
  const int yl = load_len(ylen, b);

  // Tiles are contiguous 32KB chunks in global (full D range, consecutive rows).
  const float4* xg = (const float4*)(x + (size_t)(b * N + n0) * D);
  const float4* yg = (const float4*)(y + (size_t)(b * M + m0) * D);
#pragma unroll
  for (int k = 0; k < 8; ++k) {
    int idx = tid + k * 256;     // float4 index within tile (2048 total)
    int r = idx >> 5;            // 32 float4 per row
    int c = (idx & 31) << 2;     // float offset within row
    *(float4*)&xs[r * LSTR + c] = xg[idx];
    *(float4*)&ys[r * LSTR + c] = yg[idx];
  }
  __syncthreads();

  const int tx = tid & 15;       // m group (lane bits 0..3)
  const int ty = tid >> 4;       // n group (lane bits 4..5 within wave + wave id)
  const int wv = tid >> 6;       // wave id
  float acc[4][4];
#pragma unroll
  for (int i = 0; i < 4; ++i)
#pragma unroll
    for (int j = 0; j < 4; ++j) acc[i][j] = 0.f;

  // Micro-tile is STRIDED (n = n0+ty+16i, m = m0+tx+16j): within a wave the 16
  // tx lanes hit rows tx+16j -> banks 4*tx%32 = 2-way (free); x reads broadcast.
#pragma unroll 4
  for (int dd = 0; dd < D; dd += 4) {
    float4 xa[4], yb[4];
#pragma unroll
    for (int i = 0; i < 4; ++i) xa[i] = *(const float4*)&xs[(ty + 16 * i) * LSTR + dd];
#pragma unroll
    for (int j = 0; j < 4; ++j) yb[j] = *(const float4*)&ys[(tx + 16 * j) * LSTR + dd];
#pragma unroll
    for (int i = 0; i < 4; ++i)
#pragma unroll
      for (int j = 0; j < 4; ++j) {
        acc[i][j] += fabsf(xa[i].x - yb[j].x);
        acc[i][j] += fabsf(xa[i].y - yb[j].y);
        acc[i][j] += fabsf(xa[i].z - yb[j].z);
        acc[i][j] += fabsf(xa[i].w - yb[j].w);
      }
  }

  // z store
  float* zb = z + (size_t)b * N * M;
#pragma unroll
  for (int i = 0; i < 4; ++i) {
    int n = n0 + ty + 16 * i;
#pragma unroll
    for (int j = 0; j < 4; ++j) zb[n * M + m0 + tx + 16 * j] = acc[i][j];
  }

  // ---- row partials: reduce over the 16 tx lanes (lane bits 0..3) ----
#pragma unroll
  for (int i = 0; i < 4; ++i) {
    float lm = SENT;
#pragma unroll
    for (int j = 0; j < 4; ++j)
      if (m0 + tx + 16 * j < yl) lm = fmaxf(lm, -acc[i][j]);
#pragma unroll
    for (int off = 1; off <= 8; off <<= 1) lm = fmaxf(lm, __shfl_xor(lm, off, 64));
    float ls = 0.f;
#pragma unroll
    for (int j = 0; j < 4; ++j)
      if (m0 + tx + 16 * j < yl) ls += __expf(-acc[i][j] - lm);
#pragma unroll
    for (int off = 1; off <= 8; off <<= 1) ls += __shfl_xor(ls, off, 64);
    if (tx == 0)
      rp[((b * 8 + (m0 >> 6)) * N) + n0 + ty + 16 * i] = make_float2(lm, ls);
  }

  // ---- col partials: reduce over ty within wave (lane bits 4..5), then 4 waves via LDS ----
#pragma unroll
  for (int j = 0; j < 4; ++j) {
    float cm = SENT;
#pragma unroll
    for (int i = 0; i < 4; ++i)
      if (n0 + ty + 16 * i < xl) cm = fmaxf(cm, -acc[i][j]);
    cm = fmaxf(cm, __shfl_xor(cm, 16, 64));
    cm = fmaxf(cm, __shfl_xor(cm, 32, 64));
    float cs = 0.f;
#pragma unroll
    for (int i = 0; i < 4; ++i)
      if (n0 + ty + 16 * i < xl) cs += __expf(-acc[i][j] - cm);
    cs += __shfl_xor(cs, 16, 64);
    cs += __shfl_xor(cs, 32, 64);
    if ((ty & 3) == 0) colp[wv][tx + 16 * j] = make_float2(cm, cs);
  }
  __syncthreads();
  if (tid < TM) {
    float2 p0 = colp[0][tid], p1 = colp[1][tid], p2 = colp[2][tid], p3 = colp[3][tid];
    float gm = fmaxf(fmaxf(p0.x, p1.x), fmaxf(p2.x, p3.x));
    // masked partials: sum==0 and exp(SENT-gm) underflows to 0 (or exp(0)=1 x 0) -> 0
    float gs = p0.y * __expf(p0.x - gm) + p1.y * __expf(p1.x - gm) +
               p2.y * __expf(p2.x - gm) + p3.y * __expf(p3.x - gm);
    cp[((b * 8 + (n0 >> 6)) * M) + m0 + tid] = make_float2(gm, gs);
  }
}

// Merge 8 per-tile partials per row/col with online-softmax rescale.
// idx < B*N: rows; else cols. Stores max and RECIPROCAL sum.
__global__ __launch_bounds__(256) void k_merge(const float2* __restrict__ rp,
                                               const float2* __restrict__ cp,
                                               float* __restrict__ rmax, float* __restrict__ rsuminv,
                                               float* __restrict__ cmax, float* __restrict__ csuminv) {
  int idx = blockIdx.x * 256 + threadIdx.x;         // 0 .. 2*B*512-1
  bool isrow = idx < B * N;
  int i2 = isrow ? idx : idx - B * N;               // b*512 + pos
  const float2* src = isrow ? rp : cp;
  int b = i2 >> 9, p = i2 & 511;
  float2 v[8];
  float gm = SENT;
#pragma unroll
  for (int t = 0; t < 8; ++t) {
    v[t] = src[(b * 8 + t) * 512 + p];
    gm = fmaxf(gm, v[t].x);
  }
  float gs = 0.f;
#pragma unroll
  for (int t = 0; t < 8; ++t) gs += v[t].y * __expf(v[t].x - gm);
  float inv = 1.0f / gs;                             // inf only for rows/cols never read
  if (isrow) { rmax[i2] = gm; rsuminv[i2] = inv; }
  else       { cmax[i2] = gm; csuminv[i2] = inv; }
}

__global__ __launch_bounds__(256) void k_final(const float* __restrict__ z,
                                               const int* __restrict__ xlen,
                                               const int* __restrict__ ylen,
                                               const float* __restrict__ cmax,
                                               const float* __restrict__ csuminv,
                                               const float* __restrict__ rmax,
                                               const float* __restrict__ rsuminv,
                                               float* __restrict__ acc) {
  const int b = blockIdx.y;
  const int xl = load_len(xlen, b);
  const int yl = load_len(ylen, b);
  const int n0 = blockIdx.x * 8;
  const float* zb = z + (size_t)b * N * M;
  const int tid = threadIdx.x;
  float num = 0.f, den = 0.f;
  for (int k = 0; k < 8; ++k) {
    int n = n0 + k;
    if (n >= xl) break;                    // xl uniform across block
    float rm = rmax[b * N + n];
    float ri = rsuminv[b * N + n];
    const float* zr = zb + (size_t)n * M;
    for (int m = tid; m < yl; m += 256) {
      float zv = zr[m];
      float w = -zv;
      float alpha = __expf(w - cmax[b * M + m]) * csuminv[b * M + m];
      float beta  = __expf(w - rm) * ri;
      float a = alpha + beta - alpha * beta;
      num += a * zv;
      den += a;
    }
  }
#pragma unroll
  for (int off = 32; off > 0; off >>= 1) {
    num += __shfl_xor(num, off, 64);
    den += __shfl_xor(den, off, 64);
  }
  if ((tid & 63) == 0) {
    atomicAdd(&acc[b], num);
    atomicAdd(&acc[B + b], den);
  }
}

__global__ void k_out(const float* __restrict__ acc, float* __restrict__ out) {
  int b = threadIdx.x;
  if (b < B) out[b] = -acc[b] / acc[B + b];
}

extern "C" void kernel_launch(void* const* d_in, const int* in_sizes, int n_in,
                              void* d_out, int out_size, void* d_ws, size_t ws_size,
                              hipStream_t stream) {
  const float* x    = (const float*)d_in[0];
  const float* y    = (const float*)d_in[1];
  const int*   xlen = (const int*)d_in[2];
  const int*   ylen = (const int*)d_in[3];
  float* out = (float*)d_out;

  float* ws = (float*)d_ws;
  float*  z       = ws;                    size_t off = (size_t)B * N * M;   // 4 MB
  float2* rp      = (float2*)(ws + off);   off += (size_t)B * 8 * N * 2;     // 128 KB
  float2* cp      = (float2*)(ws + off);   off += (size_t)B * 8 * M * 2;     // 128 KB
  float*  cmax    = ws + off;              off += B * M;
  float*  csuminv = ws + off;              off += B * M;
  float*  rmax    = ws + off;              off += B * N;
  float*  rsuminv = ws + off;              off += B * N;
  float*  acc     = ws + off;              off += 2 * B;

  hipMemsetAsync(acc, 0, 2 * B * sizeof(float), stream);
  k_zdiff<<<dim3(M / TM, N / TN, B), 256, 0, stream>>>(x, y, xlen, ylen, z, rp, cp);
  k_merge<<<dim3(2 * B * 512 / 256), 256, 0, stream>>>(rp, cp, rmax, rsuminv, cmax, csuminv);
  k_final<<<dim3(N / 8, B), 256, 0, stream>>>(z, xlen, ylen, cmax, csuminv, rmax, rsuminv, acc);
  k_out<<<1, 64, 0, stream>>>(acc, out);
}